// Round 4
// baseline (918.986 us; speedup 1.0000x reference)
//
#include <hip/hip_runtime.h>
#include <math.h>

#define SEQ 128
#define BATCH 32
#define EDIM 300
#define HDIM 200
#define G4 800      // 4*H
#define NGATE 1600  // 2 dirs * 4 * H

typedef _Float16 h2t __attribute__((ext_vector_type(2)));

__device__ __forceinline__ h2t u2h(unsigned v) {
    union { unsigned u; h2t h; } c; c.u = v; return c.h;
}

// v_dot2_f32_f16: acc += a.x*b.x + a.y*b.y  (f32 accumulate)
__device__ __forceinline__ float dot2acc(h2t a, h2t b, float c) {
    return __builtin_amdgcn_fdot2(a, b, c, false);
}

__device__ __forceinline__ float fast_sigmoid(float x) {
    return 1.f / (1.f + __expf(-x));
}
__device__ __forceinline__ float fast_tanh(float x) {
    x = fminf(fmaxf(x, -15.f), 15.f);
    float e = __expf(2.f * x);
    return (e - 1.f) / (e + 1.f);
}

// ------------------------------------------------------------------
// K1: embedding gather  X0[t][b][e] = emb[words[b][t]][e]
// ------------------------------------------------------------------
__global__ void k_gather(const int* __restrict__ words,
                         const float* __restrict__ emb,
                         float* __restrict__ X0)
{
    int row = blockIdx.x;          // row = t*32 + b
    int t = row >> 5;
    int b = row & 31;
    int w = words[b * SEQ + t];
    const float* src = emb + (size_t)w * EDIM;
    float* dst = X0 + (size_t)row * EDIM;
    for (int e = threadIdx.x; e < EDIM; e += blockDim.x) dst[e] = src[e];
}

// ------------------------------------------------------------------
// K2/K4: C[M x N] = A[M x K] @ B[N x K]^T + bias[N]   (f32, tiled)
// ------------------------------------------------------------------
#define BM 64
#define BN 64
#define BK 32
#define LDT 72

__global__ __launch_bounds__(256)
void k_gemm_bias(const float* __restrict__ A,
                 const float* __restrict__ Bw,
                 const float* __restrict__ bias,
                 float* __restrict__ C,
                 int M, int N, int K)
{
    __shared__ __align__(16) float As[BK][LDT];
    __shared__ __align__(16) float Bs[BK][LDT];
    int tid = threadIdx.x;
    int tx = tid & 15, ty = tid >> 4;
    int bm = blockIdx.y * BM, bn = blockIdx.x * BN;
    float acc[4][4] = {};
    for (int k0 = 0; k0 < K; k0 += BK) {
#pragma unroll
        for (int i = 0; i < 8; ++i) {
            int idx = i * 256 + tid;
            int m = idx >> 5, k = idx & 31;
            bool ok = (k0 + k) < K;
            As[k][m] = ok ? A[(size_t)(bm + m) * K + k0 + k] : 0.f;
            Bs[k][m] = ok ? Bw[(size_t)(bn + m) * K + k0 + k] : 0.f;
        }
        __syncthreads();
#pragma unroll
        for (int kk = 0; kk < BK; ++kk) {
            float4 av = *(const float4*)&As[kk][ty * 4];
            float4 bv = *(const float4*)&Bs[kk][tx * 4];
            float a0 = av.x, a1 = av.y, a2 = av.z, a3 = av.w;
            float b0 = bv.x, b1 = bv.y, b2 = bv.z, b3 = bv.w;
            acc[0][0] += a0 * b0; acc[0][1] += a0 * b1; acc[0][2] += a0 * b2; acc[0][3] += a0 * b3;
            acc[1][0] += a1 * b0; acc[1][1] += a1 * b1; acc[1][2] += a1 * b2; acc[1][3] += a1 * b3;
            acc[2][0] += a2 * b0; acc[2][1] += a2 * b1; acc[2][2] += a2 * b2; acc[2][3] += a2 * b3;
            acc[3][0] += a3 * b0; acc[3][1] += a3 * b1; acc[3][2] += a3 * b2; acc[3][3] += a3 * b3;
        }
        __syncthreads();
    }
#pragma unroll
    for (int i = 0; i < 4; ++i) {
        int m = bm + ty * 4 + i;
#pragma unroll
        for (int j = 0; j < 4; ++j) {
            int n = bn + tx * 4 + j;
            C[(size_t)m * N + n] = acc[i][j] + bias[n];
        }
    }
}

// ------------------------------------------------------------------
// K3/K5: recurrent BiLSTM layer.
// grid = 64 blocks (dir d, batch b). 256 threads = 4 waves = 1
// wave/SIMD -> 512-VGPR budget (__launch_bounds__(256,1); m08: no
// spill through 450 regs).
// Worker w < 200 owns ALL FOUR gate rows of hidden unit w:
// rows w (i), w+200 (f), w+400 (g), w+600 (o). Each row's 200 U
// weights packed fp16 into 100 named half2 regs -> 400 U-VGPRs.
// The 25 broadcast uint4 h-reads/step are shared across all 4 rows;
// activation is inline (no g_lds roundtrip, c stays in a register);
// h double-buffered in LDS -> ONE barrier per step.
// ------------------------------------------------------------------
#define REP100(X) \
    X(0)  X(1)  X(2)  X(3)  X(4)  X(5)  X(6)  X(7)  X(8)  X(9)  \
    X(10) X(11) X(12) X(13) X(14) X(15) X(16) X(17) X(18) X(19) \
    X(20) X(21) X(22) X(23) X(24) X(25) X(26) X(27) X(28) X(29) \
    X(30) X(31) X(32) X(33) X(34) X(35) X(36) X(37) X(38) X(39) \
    X(40) X(41) X(42) X(43) X(44) X(45) X(46) X(47) X(48) X(49) \
    X(50) X(51) X(52) X(53) X(54) X(55) X(56) X(57) X(58) X(59) \
    X(60) X(61) X(62) X(63) X(64) X(65) X(66) X(67) X(68) X(69) \
    X(70) X(71) X(72) X(73) X(74) X(75) X(76) X(77) X(78) X(79) \
    X(80) X(81) X(82) X(83) X(84) X(85) X(86) X(87) X(88) X(89) \
    X(90) X(91) X(92) X(93) X(94) X(95) X(96) X(97) X(98) X(99)

__global__ __launch_bounds__(256, 1)
void k_lstm(const float* __restrict__ Xg,
            const float* __restrict__ Whh,   // (2, 800, 200) f32
            float* __restrict__ Hout)
{
    int blk = blockIdx.x;      // 0..63
    int d = blk >> 5;          // direction
    int b = blk & 31;          // batch
    int w = threadIdx.x;
    bool worker = (w < HDIM);
    int rr = worker ? w : (HDIM - 1);   // clamped for safe addressing

    __shared__ __align__(16) _Float16 hbuf[2][HDIM];   // double-buffered h

    const float* UI = Whh + ((size_t)d * G4 +            rr) * HDIM;
    const float* UF = Whh + ((size_t)d * G4 + HDIM +     rr) * HDIM;
    const float* UG = Whh + ((size_t)d * G4 + 2*HDIM +   rr) * HDIM;
    const float* UO = Whh + ((size_t)d * G4 + 3*HDIM +   rr) * HDIM;

#define UDECL(i) h2t uI##i, uF##i, uG##i, uO##i;
    REP100(UDECL)
#undef UDECL

    if (worker) {
#define ULOAD(i) { float2 f_;                                                \
        f_ = *(const float2*)&UI[2*(i)];                                     \
        { h2t t_; t_.x = (_Float16)f_.x; t_.y = (_Float16)f_.y; uI##i = t_; }\
        f_ = *(const float2*)&UF[2*(i)];                                     \
        { h2t t_; t_.x = (_Float16)f_.x; t_.y = (_Float16)f_.y; uF##i = t_; }\
        f_ = *(const float2*)&UG[2*(i)];                                     \
        { h2t t_; t_.x = (_Float16)f_.x; t_.y = (_Float16)f_.y; uG##i = t_; }\
        f_ = *(const float2*)&UO[2*(i)];                                     \
        { h2t t_; t_.x = (_Float16)f_.x; t_.y = (_Float16)f_.y; uO##i = t_; }}
        REP100(ULOAD)
#undef ULOAD
    }

    if (worker) hbuf[0][w] = (_Float16)0.f;
    float c = 0.f;

    const float* xgI = Xg + (size_t)b * NGATE + (size_t)d * G4 + rr;
    const ptrdiff_t sstride = (ptrdiff_t)BATCH * NGATE;

    __syncthreads();

    int tt0 = d ? (SEQ - 1) : 0;
    float xI_c = 0.f, xF_c = 0.f, xG_c = 0.f, xO_c = 0.f;
    if (worker) {
        const float* p = xgI + (ptrdiff_t)tt0 * sstride;
        xI_c = p[0]; xF_c = p[HDIM]; xG_c = p[2*HDIM]; xO_c = p[3*HDIM];
    }

    const _Float16* hcur = hbuf[0];
    _Float16* hnxt = hbuf[1];

#define DOTQ(q, i0, i1, i2, i3) {                                           \
    uint4 hw_ = *(const uint4*)&hcur[8*(q)];                                \
    h2t h0_ = u2h(hw_.x), h1_ = u2h(hw_.y);                                 \
    h2t h2_ = u2h(hw_.z), h3_ = u2h(hw_.w);                                 \
    aI = dot2acc(uI##i0, h0_, aI); aF = dot2acc(uF##i0, h0_, aF);           \
    aG = dot2acc(uG##i0, h0_, aG); aO = dot2acc(uO##i0, h0_, aO);           \
    aI = dot2acc(uI##i1, h1_, aI); aF = dot2acc(uF##i1, h1_, aF);           \
    aG = dot2acc(uG##i1, h1_, aG); aO = dot2acc(uO##i1, h1_, aO);           \
    aI = dot2acc(uI##i2, h2_, aI); aF = dot2acc(uF##i2, h2_, aF);           \
    aG = dot2acc(uG##i2, h2_, aG); aO = dot2acc(uO##i2, h2_, aO);           \
    aI = dot2acc(uI##i3, h3_, aI); aF = dot2acc(uF##i3, h3_, aF);           \
    aG = dot2acc(uG##i3, h3_, aG); aO = dot2acc(uO##i3, h3_, aO); }

#pragma unroll 1
    for (int t = 0; t < SEQ; ++t) {
        int tt = d ? (SEQ - 1 - t) : t;
        if (worker) {
            float xI_n = 0.f, xF_n = 0.f, xG_n = 0.f, xO_n = 0.f;
            if (t + 1 < SEQ) {
                const float* p = xgI + (ptrdiff_t)(d ? (SEQ-2-t) : (t+1)) * sstride;
                xI_n = p[0]; xF_n = p[HDIM]; xG_n = p[2*HDIM]; xO_n = p[3*HDIM];
            }
            float aI = xI_c, aF = xF_c, aG = xG_c, aO = xO_c;
            DOTQ( 0,  0,  1,  2,  3)
            DOTQ( 1,  4,  5,  6,  7)
            DOTQ( 2,  8,  9, 10, 11)
            DOTQ( 3, 12, 13, 14, 15)
            DOTQ( 4, 16, 17, 18, 19)
            DOTQ( 5, 20, 21, 22, 23)
            DOTQ( 6, 24, 25, 26, 27)
            DOTQ( 7, 28, 29, 30, 31)
            DOTQ( 8, 32, 33, 34, 35)
            DOTQ( 9, 36, 37, 38, 39)
            DOTQ(10, 40, 41, 42, 43)
            DOTQ(11, 44, 45, 46, 47)
            DOTQ(12, 48, 49, 50, 51)
            DOTQ(13, 52, 53, 54, 55)
            DOTQ(14, 56, 57, 58, 59)
            DOTQ(15, 60, 61, 62, 63)
            DOTQ(16, 64, 65, 66, 67)
            DOTQ(17, 68, 69, 70, 71)
            DOTQ(18, 72, 73, 74, 75)
            DOTQ(19, 76, 77, 78, 79)
            DOTQ(20, 80, 81, 82, 83)
            DOTQ(21, 84, 85, 86, 87)
            DOTQ(22, 88, 89, 90, 91)
            DOTQ(23, 92, 93, 94, 95)
            DOTQ(24, 96, 97, 98, 99)
            float si = fast_sigmoid(aI);
            float sf = fast_sigmoid(aF);
            float so = fast_sigmoid(aO);
            c = sf * c + si * fast_tanh(aG);
            float hh = so * fast_tanh(c);
            hnxt[w] = (_Float16)hh;
            Hout[((size_t)tt * BATCH + b) * (2 * HDIM) + d * HDIM + w] = hh;
            xI_c = xI_n; xF_c = xF_n; xG_c = xG_n; xO_c = xO_n;
        }
        __syncthreads();
        const _Float16* tmp = hcur; hcur = hnxt; hnxt = (_Float16*)tmp;
    }
#undef DOTQ
}

// ------------------------------------------------------------------
// K6: out[b][s][o] = sigmoid(H1[s][b][:] . Wo[o][:] + bo[o])
// ------------------------------------------------------------------
__global__ void k_out(const float* __restrict__ H1,
                      const float* __restrict__ Wo,
                      const float* __restrict__ bo,
                      float* __restrict__ out)
{
    int idx = blockIdx.x * blockDim.x + threadIdx.x;
    if (idx >= BATCH * SEQ * 17) return;
    int o = idx % 17;
    int bs = idx / 17;
    int b = bs >> 7;      // /128
    int s = bs & 127;
    const float* hrow = H1 + ((size_t)(s * BATCH + b)) * (2 * HDIM);
    const float* wrow = Wo + (size_t)o * (2 * HDIM);
    float acc = bo[o];
#pragma unroll 4
    for (int j = 0; j < 2 * HDIM; ++j) acc += hrow[j] * wrow[j];
    out[idx] = 1.f / (1.f + __expf(-acc));
}

// ------------------------------------------------------------------
extern "C" void kernel_launch(void* const* d_in, const int* in_sizes, int n_in,
                              void* d_out, int out_size, void* d_ws, size_t ws_size,
                              hipStream_t stream)
{
    const int*   words = (const int*)d_in[0];
    // d_in[1] chars, d_in[2] lens: dead code in the reference
    const float* emb   = (const float*)d_in[3];
    // d_in[4..6]: char conv params, dead
    const float* Wih0  = (const float*)d_in[7];
    const float* Whh0  = (const float*)d_in[8];
    const float* b0    = (const float*)d_in[9];
    const float* Wih1  = (const float*)d_in[10];
    const float* Whh1  = (const float*)d_in[11];
    const float* b1    = (const float*)d_in[12];
    const float* Wo    = (const float*)d_in[13];
    const float* bo    = (const float*)d_in[14];
    float* out = (float*)d_out;

    char* ws = (char*)d_ws;
    const size_t X0_OFF = 0;
    const size_t XG_OFF = X0_OFF + (size_t)SEQ * BATCH * EDIM * 4;          // 4.9 MB
    const size_t H0_OFF = XG_OFF + (size_t)SEQ * BATCH * NGATE * 4;         // +26.2 MB
    const size_t H1_OFF = H0_OFF + (size_t)SEQ * BATCH * 2 * HDIM * 4;      // +6.6 MB
    float* X0 = (float*)(ws + X0_OFF);
    float* Xg = (float*)(ws + XG_OFF);
    float* H0 = (float*)(ws + H0_OFF);
    float* H1 = (float*)(ws + H1_OFF);

    // 1. gather embeddings -> X0 (S, B, 300)
    k_gather<<<SEQ * BATCH, 128, 0, stream>>>(words, emb, X0);

    // 2. layer-0 input GEMM: Xg = X0 @ Wih0^T + b0   (4096 x 1600, K=300)
    dim3 gemm_grid(NGATE / BN, (SEQ * BATCH) / BM);
    k_gemm_bias<<<gemm_grid, 256, 0, stream>>>(X0, Wih0, b0, Xg,
                                               SEQ * BATCH, NGATE, EDIM);

    // 3. layer-0 recurrence -> H0 (S, B, 400)
    k_lstm<<<64, 256, 0, stream>>>(Xg, Whh0, H0);

    // 4. layer-1 input GEMM: Xg = H0 @ Wih1^T + b1   (4096 x 1600, K=400)
    k_gemm_bias<<<gemm_grid, 256, 0, stream>>>(H0, Wih1, b1, Xg,
                                               SEQ * BATCH, NGATE, 2 * HDIM);

    // 5. layer-1 recurrence -> H1
    k_lstm<<<64, 256, 0, stream>>>(Xg, Whh1, H1);

    // 6. output head
    int nout = BATCH * SEQ * 17;
    k_out<<<(nout + 255) / 256, 256, 0, stream>>>(H1, Wo, bo, out);
}

// Round 5
// 839.291 us; speedup vs baseline: 1.0950x; 1.0950x over previous
//
#include <hip/hip_runtime.h>
#include <math.h>

#define SEQ 128
#define BATCH 32
#define EDIM 300
#define HDIM 200
#define G4 800      // 4*H
#define NGATE 1600  // 2 dirs * 4 * H
#define KC 25       // 25 chunks of 8 halves = 200 k-values
#define PERSIST 10  // chunks held in registers across all steps
#define CHSTRIDE 6400   // halves between k-chunks in Upk: 800 rows * 8

typedef _Float16 h2t __attribute__((ext_vector_type(2)));

__device__ __forceinline__ h2t u2h(unsigned v) {
    union { unsigned u; h2t h; } c; c.u = v; return c.h;
}

// v_dot2_f32_f16: acc += a.x*b.x + a.y*b.y  (f32 accumulate)
__device__ __forceinline__ float dot2acc(h2t a, h2t b, float c) {
    return __builtin_amdgcn_fdot2(a, b, c, false);
}

// 8 halves x 8 halves -> acc (4 dot2)
__device__ __forceinline__ float dot8(uint4 u, uint4 h, float acc) {
    acc = dot2acc(u2h(u.x), u2h(h.x), acc);
    acc = dot2acc(u2h(u.y), u2h(h.y), acc);
    acc = dot2acc(u2h(u.z), u2h(h.z), acc);
    acc = dot2acc(u2h(u.w), u2h(h.w), acc);
    return acc;
}

__device__ __forceinline__ float fast_sigmoid(float x) {
    return 1.f / (1.f + __expf(-x));
}
__device__ __forceinline__ float fast_tanh(float x) {
    x = fminf(fmaxf(x, -15.f), 15.f);
    float e = __expf(2.f * x);
    return (e - 1.f) / (e + 1.f);
}

// ------------------------------------------------------------------
// K1: embedding gather  X0[t][b][e] = emb[words[b][t]][e]
// ------------------------------------------------------------------
__global__ void k_gather(const int* __restrict__ words,
                         const float* __restrict__ emb,
                         float* __restrict__ X0)
{
    int row = blockIdx.x;          // row = t*32 + b
    int t = row >> 5;
    int b = row & 31;
    int w = words[b * SEQ + t];
    const float* src = emb + (size_t)w * EDIM;
    float* dst = X0 + (size_t)row * EDIM;
    for (int e = threadIdx.x; e < EDIM; e += blockDim.x) dst[e] = src[e];
}

// ------------------------------------------------------------------
// K1b: pack Whh (2,800,200) f32 -> Upk fp16, chunk-major coalesced:
//   Upk[((d*KC + kc)*800 + r)*8 + j] = Whh[d][r][kc*8 + j]
// One thread per 16B chunk; consecutive idx -> consecutive writes.
// ------------------------------------------------------------------
__global__ void k_pack(const float* __restrict__ Whh,
                       _Float16* __restrict__ Upk)
{
    int idx = blockIdx.x * blockDim.x + threadIdx.x;   // (d*KC+kc)*800 + r
    if (idx >= 2 * KC * 800) return;
    int r  = idx % 800;
    int kc = (idx / 800) % KC;
    int d  = idx / (800 * KC);
    const float* src = Whh + ((size_t)d * G4 + r) * HDIM + kc * 8;
    _Float16* dst = Upk + (size_t)idx * 8;
#pragma unroll
    for (int j = 0; j < 8; ++j) dst[j] = (_Float16)src[j];
}

// ------------------------------------------------------------------
// K2/K4: C[M x N] = A[M x K] @ B[N x K]^T + bias[N]   (f32, tiled)
// ------------------------------------------------------------------
#define BM 64
#define BN 64
#define BK 32
#define LDT 72

__global__ __launch_bounds__(256)
void k_gemm_bias(const float* __restrict__ A,
                 const float* __restrict__ Bw,
                 const float* __restrict__ bias,
                 float* __restrict__ C,
                 int M, int N, int K)
{
    __shared__ __align__(16) float As[BK][LDT];
    __shared__ __align__(16) float Bs[BK][LDT];
    int tid = threadIdx.x;
    int tx = tid & 15, ty = tid >> 4;
    int bm = blockIdx.y * BM, bn = blockIdx.x * BN;
    float acc[4][4] = {};
    for (int k0 = 0; k0 < K; k0 += BK) {
#pragma unroll
        for (int i = 0; i < 8; ++i) {
            int idx = i * 256 + tid;
            int m = idx >> 5, k = idx & 31;
            bool ok = (k0 + k) < K;
            As[k][m] = ok ? A[(size_t)(bm + m) * K + k0 + k] : 0.f;
            Bs[k][m] = ok ? Bw[(size_t)(bn + m) * K + k0 + k] : 0.f;
        }
        __syncthreads();
#pragma unroll
        for (int kk = 0; kk < BK; ++kk) {
            float4 av = *(const float4*)&As[kk][ty * 4];
            float4 bv = *(const float4*)&Bs[kk][tx * 4];
            float a0 = av.x, a1 = av.y, a2 = av.z, a3 = av.w;
            float b0 = bv.x, b1 = bv.y, b2 = bv.z, b3 = bv.w;
            acc[0][0] += a0 * b0; acc[0][1] += a0 * b1; acc[0][2] += a0 * b2; acc[0][3] += a0 * b3;
            acc[1][0] += a1 * b0; acc[1][1] += a1 * b1; acc[1][2] += a1 * b2; acc[1][3] += a1 * b3;
            acc[2][0] += a2 * b0; acc[2][1] += a2 * b1; acc[2][2] += a2 * b2; acc[2][3] += a2 * b3;
            acc[3][0] += a3 * b0; acc[3][1] += a3 * b1; acc[3][2] += a3 * b2; acc[3][3] += a3 * b3;
        }
        __syncthreads();
    }
#pragma unroll
    for (int i = 0; i < 4; ++i) {
        int m = bm + ty * 4 + i;
#pragma unroll
        for (int j = 0; j < 4; ++j) {
            int n = bn + tx * 4 + j;
            C[(size_t)m * N + n] = acc[i][j] + bias[n];
        }
    }
}

// ------------------------------------------------------------------
// K3/K5: recurrent BiLSTM layer, L2-streamed fp16 U.
// grid = 64 blocks (dir d, batch b). 832 threads = 13 waves
// (~3-4/SIMD -> ~128-VGPR budget; allocator-friendly, good TLP).
// Worker r < 800 owns one gate row. Per step: 10 persistent
// register chunks + 15 streamed coalesced uint4 loads from L2
// (lane r reads Upk[(d,kc)][r] -> consecutive 16B across lanes),
// 100 dot2 total, g_lds exchange, 200 threads do activation.
// ------------------------------------------------------------------
#define REPP(X) X(0) X(1) X(2) X(3) X(4) X(5) X(6) X(7) X(8) X(9)

__global__ __launch_bounds__(832)
void k_lstm(const float* __restrict__ Xg,
            const _Float16* __restrict__ Upk,  // (2, KC, 800, 8) halves
            float* __restrict__ Hout)
{
    int blk = blockIdx.x;      // 0..63
    int d = blk >> 5;          // direction
    int b = blk & 31;          // batch
    int r = threadIdx.x;       // gate row
    int rr = (r < G4) ? r : (G4 - 1);   // clamped

    __shared__ __align__(16) _Float16 hbuf[2][HDIM];
    __shared__ float g_lds[G4];

    // per-thread base: chunk kc of this row at up_ptr + kc*CHSTRIDE (halves)
    const _Float16* up_ptr = Upk + ((size_t)d * KC * 800 + rr) * 8;

    // persistent chunks 0..9 (40 VGPRs)
#define PDECL(i) uint4 p##i = *(const uint4*)(up_ptr + (size_t)(i) * CHSTRIDE);
    REPP(PDECL)
#undef PDECL

    if (r < HDIM) hbuf[0][r] = (_Float16)0.f;
    float c = 0.f;

    const float* xg_ptr = Xg + (size_t)b * NGATE + (size_t)d * G4 + rr;
    const ptrdiff_t sstride = (ptrdiff_t)BATCH * NGATE;

    __syncthreads();

    int tt0 = d ? (SEQ - 1) : 0;
    float xg_c = xg_ptr[(ptrdiff_t)tt0 * sstride];

    const _Float16* hcur = hbuf[0];
    _Float16* hnxt = hbuf[1];

#pragma unroll 1
    for (int t = 0; t < SEQ; ++t) {
        int tt = d ? (SEQ - 1 - t) : t;
        // prefetch next step's Xg element
        float xg_n = 0.f;
        if (t + 1 < SEQ)
            xg_n = xg_ptr[(ptrdiff_t)(d ? (SEQ - 2 - t) : (t + 1)) * sstride];

        float a0 = xg_c, a1 = 0.f;
        // persistent chunks (h broadcast reads: same-address uint4)
#define PDOT(i) { uint4 hv_ = *(const uint4*)&hcur[8 * (i)];                \
                  if ((i) & 1) a1 = dot8(p##i, hv_, a1);                    \
                  else         a0 = dot8(p##i, hv_, a0); }
        REPP(PDOT)
#undef PDOT
        // streamed chunks from L2 (coalesced across lanes)
#pragma unroll
        for (int kc = PERSIST; kc < KC; ++kc) {
            uint4 uv = *(const uint4*)(up_ptr + (size_t)kc * CHSTRIDE);
            uint4 hv = *(const uint4*)&hcur[8 * kc];
            if (kc & 1) a1 = dot8(uv, hv, a1);
            else        a0 = dot8(uv, hv, a0);
        }
        if (r < G4) g_lds[r] = a0 + a1;
        __syncthreads();

        if (r < HDIM) {
            float gi = g_lds[r];
            float gf = g_lds[HDIM + r];
            float gg = g_lds[2 * HDIM + r];
            float go = g_lds[3 * HDIM + r];
            float si = fast_sigmoid(gi);
            float sf = fast_sigmoid(gf);
            float so = fast_sigmoid(go);
            c = sf * c + si * fast_tanh(gg);
            float hh = so * fast_tanh(c);
            hnxt[r] = (_Float16)hh;
            Hout[((size_t)tt * BATCH + b) * (2 * HDIM) + d * HDIM + r] = hh;
        }
        __syncthreads();

        const _Float16* tmp = hcur; hcur = hnxt; hnxt = (_Float16*)tmp;
        xg_c = xg_n;
    }
}

// ------------------------------------------------------------------
// K6: out[b][s][o] = sigmoid(H1[s][b][:] . Wo[o][:] + bo[o])
// ------------------------------------------------------------------
__global__ void k_out(const float* __restrict__ H1,
                      const float* __restrict__ Wo,
                      const float* __restrict__ bo,
                      float* __restrict__ out)
{
    int idx = blockIdx.x * blockDim.x + threadIdx.x;
    if (idx >= BATCH * SEQ * 17) return;
    int o = idx % 17;
    int bs = idx / 17;
    int b = bs >> 7;      // /128
    int s = bs & 127;
    const float* hrow = H1 + ((size_t)(s * BATCH + b)) * (2 * HDIM);
    const float* wrow = Wo + (size_t)o * (2 * HDIM);
    float acc = bo[o];
#pragma unroll 4
    for (int j = 0; j < 2 * HDIM; ++j) acc += hrow[j] * wrow[j];
    out[idx] = 1.f / (1.f + __expf(-acc));
}

// ------------------------------------------------------------------
extern "C" void kernel_launch(void* const* d_in, const int* in_sizes, int n_in,
                              void* d_out, int out_size, void* d_ws, size_t ws_size,
                              hipStream_t stream)
{
    const int*   words = (const int*)d_in[0];
    // d_in[1] chars, d_in[2] lens: dead code in the reference
    const float* emb   = (const float*)d_in[3];
    // d_in[4..6]: char conv params, dead
    const float* Wih0  = (const float*)d_in[7];
    const float* Whh0  = (const float*)d_in[8];
    const float* b0    = (const float*)d_in[9];
    const float* Wih1  = (const float*)d_in[10];
    const float* Whh1  = (const float*)d_in[11];
    const float* b1    = (const float*)d_in[12];
    const float* Wo    = (const float*)d_in[13];
    const float* bo    = (const float*)d_in[14];
    float* out = (float*)d_out;

    char* ws = (char*)d_ws;
    const size_t X0_OFF = 0;
    const size_t XG_OFF = X0_OFF + (size_t)SEQ * BATCH * EDIM * 4;          // 4.9 MB
    const size_t H0_OFF = XG_OFF + (size_t)SEQ * BATCH * NGATE * 4;         // +26.2 MB
    const size_t H1_OFF = H0_OFF + (size_t)SEQ * BATCH * 2 * HDIM * 4;      // +6.6 MB
    float* X0 = (float*)(ws + X0_OFF);
    float* Xg = (float*)(ws + XG_OFF);
    float* H0 = (float*)(ws + H0_OFF);
    float* H1 = (float*)(ws + H1_OFF);
    // Upk0/Upk1 overlay the X0 region (X0 is dead after the layer-0 GEMM;
    // pack kernels run after that GEMM). 640 KB each, X0 region is 4.9 MB.
    _Float16* Upk0 = (_Float16*)(ws + X0_OFF);
    _Float16* Upk1 = Upk0 + (size_t)2 * KC * 800 * 8;

    // 1. gather embeddings -> X0 (S, B, 300)
    k_gather<<<SEQ * BATCH, 128, 0, stream>>>(words, emb, X0);

    // 2. layer-0 input GEMM: Xg = X0 @ Wih0^T + b0   (4096 x 1600, K=300)
    dim3 gemm_grid(NGATE / BN, (SEQ * BATCH) / BM);
    k_gemm_bias<<<gemm_grid, 256, 0, stream>>>(X0, Wih0, b0, Xg,
                                               SEQ * BATCH, NGATE, EDIM);

    // 2b. pack recurrent weights to fp16 (X0 dead from here on)
    int npack = 2 * KC * 800;
    k_pack<<<(npack + 255) / 256, 256, 0, stream>>>(Whh0, Upk0);
    k_pack<<<(npack + 255) / 256, 256, 0, stream>>>(Whh1, Upk1);

    // 3. layer-0 recurrence -> H0 (S, B, 400)
    k_lstm<<<64, 832, 0, stream>>>(Xg, Upk0, H0);

    // 4. layer-1 input GEMM: Xg = H0 @ Wih1^T + b1   (4096 x 1600, K=400)
    k_gemm_bias<<<gemm_grid, 256, 0, stream>>>(H0, Wih1, b1, Xg,
                                               SEQ * BATCH, NGATE, 2 * HDIM);

    // 5. layer-1 recurrence -> H1
    k_lstm<<<64, 832, 0, stream>>>(Xg, Upk1, H1);

    // 6. output head
    int nout = BATCH * SEQ * 17;
    k_out<<<(nout + 255) / 256, 256, 0, stream>>>(H1, Wo, bo, out);
}

// Round 6
// 649.505 us; speedup vs baseline: 1.4149x; 1.2922x over previous
//
#include <hip/hip_runtime.h>
#include <math.h>

#define SEQ 128
#define BATCH 32
#define EDIM 300
#define HDIM 200
#define G4 800      // 4*H
#define NGATE 1600  // 2 dirs * 4 * H
#define KC 25       // 25 chunks of 8 halves = 200 k-values
#define PERSIST 21  // chunks held in registers across all steps
#define NLDS 4      // chunks held in LDS (PERSIST + NLDS == KC)
#define CHSTRIDE 6400   // halves between k-chunks in Upk: 800 rows * 8

typedef _Float16 h2t __attribute__((ext_vector_type(2)));

__device__ __forceinline__ h2t u2h(unsigned v) {
    union { unsigned u; h2t h; } c; c.u = v; return c.h;
}

// v_dot2_f32_f16: acc += a.x*b.x + a.y*b.y  (f32 accumulate)
__device__ __forceinline__ float dot2acc(h2t a, h2t b, float c) {
    return __builtin_amdgcn_fdot2(a, b, c, false);
}

// 8 halves x 8 halves -> acc (4 dot2)
__device__ __forceinline__ float dot8(uint4 u, uint4 h, float acc) {
    acc = dot2acc(u2h(u.x), u2h(h.x), acc);
    acc = dot2acc(u2h(u.y), u2h(h.y), acc);
    acc = dot2acc(u2h(u.z), u2h(h.z), acc);
    acc = dot2acc(u2h(u.w), u2h(h.w), acc);
    return acc;
}

__device__ __forceinline__ float fast_sigmoid(float x) {
    return 1.f / (1.f + __expf(-x));
}
__device__ __forceinline__ float fast_tanh(float x) {
    x = fminf(fmaxf(x, -15.f), 15.f);
    float e = __expf(2.f * x);
    return (e - 1.f) / (e + 1.f);
}

// ------------------------------------------------------------------
// K1: embedding gather  X0[t][b][e] = emb[words[b][t]][e]
// ------------------------------------------------------------------
__global__ void k_gather(const int* __restrict__ words,
                         const float* __restrict__ emb,
                         float* __restrict__ X0)
{
    int row = blockIdx.x;          // row = t*32 + b
    int t = row >> 5;
    int b = row & 31;
    int w = words[b * SEQ + t];
    const float* src = emb + (size_t)w * EDIM;
    float* dst = X0 + (size_t)row * EDIM;
    for (int e = threadIdx.x; e < EDIM; e += blockDim.x) dst[e] = src[e];
}

// ------------------------------------------------------------------
// K1b: pack Whh (2,800,200) f32 -> Upk fp16, chunk-major coalesced:
//   Upk[((d*KC + kc)*800 + r)*8 + j] = Whh[d][r][kc*8 + j]
// ------------------------------------------------------------------
__global__ void k_pack(const float* __restrict__ Whh,
                       _Float16* __restrict__ Upk)
{
    int idx = blockIdx.x * blockDim.x + threadIdx.x;   // (d*KC+kc)*800 + r
    if (idx >= 2 * KC * 800) return;
    int r  = idx % 800;
    int kc = (idx / 800) % KC;
    int d  = idx / (800 * KC);
    const float* src = Whh + ((size_t)d * G4 + r) * HDIM + kc * 8;
    _Float16* dst = Upk + (size_t)idx * 8;
#pragma unroll
    for (int j = 0; j < 8; ++j) dst[j] = (_Float16)src[j];
}

// ------------------------------------------------------------------
// K2/K4: C[M x N] = A[M x K] @ B[N x K]^T + bias[N]   (f32, tiled)
// ------------------------------------------------------------------
#define BM 64
#define BN 64
#define BK 32
#define LDT 72

__global__ __launch_bounds__(256)
void k_gemm_bias(const float* __restrict__ A,
                 const float* __restrict__ Bw,
                 const float* __restrict__ bias,
                 float* __restrict__ C,
                 int M, int N, int K)
{
    __shared__ __align__(16) float As[BK][LDT];
    __shared__ __align__(16) float Bs[BK][LDT];
    int tid = threadIdx.x;
    int tx = tid & 15, ty = tid >> 4;
    int bm = blockIdx.y * BM, bn = blockIdx.x * BN;
    float acc[4][4] = {};
    for (int k0 = 0; k0 < K; k0 += BK) {
#pragma unroll
        for (int i = 0; i < 8; ++i) {
            int idx = i * 256 + tid;
            int m = idx >> 5, k = idx & 31;
            bool ok = (k0 + k) < K;
            As[k][m] = ok ? A[(size_t)(bm + m) * K + k0 + k] : 0.f;
            Bs[k][m] = ok ? Bw[(size_t)(bn + m) * K + k0 + k] : 0.f;
        }
        __syncthreads();
#pragma unroll
        for (int kk = 0; kk < BK; ++kk) {
            float4 av = *(const float4*)&As[kk][ty * 4];
            float4 bv = *(const float4*)&Bs[kk][tx * 4];
            float a0 = av.x, a1 = av.y, a2 = av.z, a3 = av.w;
            float b0 = bv.x, b1 = bv.y, b2 = bv.z, b3 = bv.w;
            acc[0][0] += a0 * b0; acc[0][1] += a0 * b1; acc[0][2] += a0 * b2; acc[0][3] += a0 * b3;
            acc[1][0] += a1 * b0; acc[1][1] += a1 * b1; acc[1][2] += a1 * b2; acc[1][3] += a1 * b3;
            acc[2][0] += a2 * b0; acc[2][1] += a2 * b1; acc[2][2] += a2 * b2; acc[2][3] += a2 * b3;
            acc[3][0] += a3 * b0; acc[3][1] += a3 * b1; acc[3][2] += a3 * b2; acc[3][3] += a3 * b3;
        }
        __syncthreads();
    }
#pragma unroll
    for (int i = 0; i < 4; ++i) {
        int m = bm + ty * 4 + i;
#pragma unroll
        for (int j = 0; j < 4; ++j) {
            int n = bn + tx * 4 + j;
            C[(size_t)m * N + n] = acc[i][j] + bias[n];
        }
    }
}

// ------------------------------------------------------------------
// K3/K5: recurrent BiLSTM layer. U fully CU-resident:
//   chunks 0..20 in registers (21 x uint4 = 84 VGPR/thread),
//   chunks 21..24 in LDS (4 x 800 x 16B = 51.2 KB).
// Zero L2 weight streaming in steady state (R5 was L2-BW-bound at
// ~34 B/cyc/CU on 15 streamed chunks).
// grid = 64 blocks (dir d, batch b). 832 threads = 13 waves
// (cap 128 VGPR; request ~115 -> feasible, R5 showed allocator
// takes what's needed when under cap).
// ------------------------------------------------------------------
#define REPP(X) X(0) X(1) X(2) X(3) X(4) X(5) X(6) X(7) X(8) X(9) \
                X(10) X(11) X(12) X(13) X(14) X(15) X(16) X(17) X(18) X(19) X(20)

__global__ __launch_bounds__(832)
void k_lstm(const float* __restrict__ Xg,
            const _Float16* __restrict__ Upk,  // (2, KC, 800, 8) halves
            float* __restrict__ Hout)
{
    int blk = blockIdx.x;      // 0..63
    int d = blk >> 5;          // direction
    int b = blk & 31;          // batch
    int r = threadIdx.x;       // gate row
    int rr = (r < G4) ? r : (G4 - 1);   // clamped

    __shared__ __align__(16) _Float16 hbuf[2][HDIM];
    __shared__ float g_lds[G4];
    __shared__ __align__(16) _Float16 lds_u[NLDS][800][8];  // 51.2 KB

    // per-thread base: chunk kc of this row at up_ptr + kc*CHSTRIDE (halves)
    const _Float16* up_ptr = Upk + ((size_t)d * KC * 800 + rr) * 8;

    // persistent chunks 0..20 (84 VGPRs)
#define PDECL(i) uint4 p##i = *(const uint4*)(up_ptr + (size_t)(i) * CHSTRIDE);
    REPP(PDECL)
#undef PDECL

    // LDS chunks 21..24: each worker writes its own row (coalesced-ish,
    // 2-way bank overlap = free)
    if (r < G4) {
#pragma unroll
        for (int j = 0; j < NLDS; ++j)
            *(uint4*)&lds_u[j][r][0] =
                *(const uint4*)(up_ptr + (size_t)(PERSIST + j) * CHSTRIDE);
    }

    if (r < HDIM) hbuf[0][r] = (_Float16)0.f;
    float c = 0.f;

    const float* xg_ptr = Xg + (size_t)b * NGATE + (size_t)d * G4 + rr;
    const ptrdiff_t sstride = (ptrdiff_t)BATCH * NGATE;

    __syncthreads();

    int tt0 = d ? (SEQ - 1) : 0;
    float xg_c = xg_ptr[(ptrdiff_t)tt0 * sstride];

    const _Float16* hcur = hbuf[0];
    _Float16* hnxt = hbuf[1];

#pragma unroll 1
    for (int t = 0; t < SEQ; ++t) {
        int tt = d ? (SEQ - 1 - t) : t;
        // prefetch next step's Xg element
        float xg_n = 0.f;
        if (t + 1 < SEQ)
            xg_n = xg_ptr[(ptrdiff_t)(d ? (SEQ - 2 - t) : (t + 1)) * sstride];

        float a0 = xg_c, a1 = 0.f;
        // persistent chunks (h broadcast reads: same-address uint4)
#define PDOT(i) { uint4 hv_ = *(const uint4*)&hcur[8 * (i)];                \
                  if ((i) & 1) a1 = dot8(p##i, hv_, a1);                    \
                  else         a0 = dot8(p##i, hv_, a0); }
        REPP(PDOT)
#undef PDOT
        // LDS-resident chunks 21..24
#pragma unroll
        for (int j = 0; j < NLDS; ++j) {
            uint4 uv = *(const uint4*)&lds_u[j][rr][0];
            uint4 hv = *(const uint4*)&hcur[8 * (PERSIST + j)];
            if ((PERSIST + j) & 1) a1 = dot8(uv, hv, a1);
            else                   a0 = dot8(uv, hv, a0);
        }
        if (r < G4) g_lds[r] = a0 + a1;
        __syncthreads();

        if (r < HDIM) {
            float gi = g_lds[r];
            float gf = g_lds[HDIM + r];
            float gg = g_lds[2 * HDIM + r];
            float go = g_lds[3 * HDIM + r];
            float si = fast_sigmoid(gi);
            float sf = fast_sigmoid(gf);
            float so = fast_sigmoid(go);
            c = sf * c + si * fast_tanh(gg);
            float hh = so * fast_tanh(c);
            hnxt[r] = (_Float16)hh;
            Hout[((size_t)tt * BATCH + b) * (2 * HDIM) + d * HDIM + r] = hh;
        }
        __syncthreads();

        const _Float16* tmp = hcur; hcur = hnxt; hnxt = (_Float16*)tmp;
        xg_c = xg_n;
    }
}

// ------------------------------------------------------------------
// K6: out[b][s][o] = sigmoid(H1[s][b][:] . Wo[o][:] + bo[o])
// ------------------------------------------------------------------
__global__ void k_out(const float* __restrict__ H1,
                      const float* __restrict__ Wo,
                      const float* __restrict__ bo,
                      float* __restrict__ out)
{
    int idx = blockIdx.x * blockDim.x + threadIdx.x;
    if (idx >= BATCH * SEQ * 17) return;
    int o = idx % 17;
    int bs = idx / 17;
    int b = bs >> 7;      // /128
    int s = bs & 127;
    const float* hrow = H1 + ((size_t)(s * BATCH + b)) * (2 * HDIM);
    const float* wrow = Wo + (size_t)o * (2 * HDIM);
    float acc = bo[o];
#pragma unroll 4
    for (int j = 0; j < 2 * HDIM; ++j) acc += hrow[j] * wrow[j];
    out[idx] = 1.f / (1.f + __expf(-acc));
}

// ------------------------------------------------------------------
extern "C" void kernel_launch(void* const* d_in, const int* in_sizes, int n_in,
                              void* d_out, int out_size, void* d_ws, size_t ws_size,
                              hipStream_t stream)
{
    const int*   words = (const int*)d_in[0];
    // d_in[1] chars, d_in[2] lens: dead code in the reference
    const float* emb   = (const float*)d_in[3];
    // d_in[4..6]: char conv params, dead
    const float* Wih0  = (const float*)d_in[7];
    const float* Whh0  = (const float*)d_in[8];
    const float* b0    = (const float*)d_in[9];
    const float* Wih1  = (const float*)d_in[10];
    const float* Whh1  = (const float*)d_in[11];
    const float* b1    = (const float*)d_in[12];
    const float* Wo    = (const float*)d_in[13];
    const float* bo    = (const float*)d_in[14];
    float* out = (float*)d_out;

    char* ws = (char*)d_ws;
    const size_t X0_OFF = 0;
    const size_t XG_OFF = X0_OFF + (size_t)SEQ * BATCH * EDIM * 4;          // 4.9 MB
    const size_t H0_OFF = XG_OFF + (size_t)SEQ * BATCH * NGATE * 4;         // +26.2 MB
    const size_t H1_OFF = H0_OFF + (size_t)SEQ * BATCH * 2 * HDIM * 4;      // +6.6 MB
    float* X0 = (float*)(ws + X0_OFF);
    float* Xg = (float*)(ws + XG_OFF);
    float* H0 = (float*)(ws + H0_OFF);
    float* H1 = (float*)(ws + H1_OFF);
    // Upk0/Upk1 overlay the X0 region (X0 dead after the layer-0 GEMM).
    _Float16* Upk0 = (_Float16*)(ws + X0_OFF);
    _Float16* Upk1 = Upk0 + (size_t)2 * KC * 800 * 8;

    // 1. gather embeddings -> X0 (S, B, 300)
    k_gather<<<SEQ * BATCH, 128, 0, stream>>>(words, emb, X0);

    // 2. layer-0 input GEMM: Xg = X0 @ Wih0^T + b0   (4096 x 1600, K=300)
    dim3 gemm_grid(NGATE / BN, (SEQ * BATCH) / BM);
    k_gemm_bias<<<gemm_grid, 256, 0, stream>>>(X0, Wih0, b0, Xg,
                                               SEQ * BATCH, NGATE, EDIM);

    // 2b. pack recurrent weights to fp16 (X0 dead from here on)
    int npack = 2 * KC * 800;
    k_pack<<<(npack + 255) / 256, 256, 0, stream>>>(Whh0, Upk0);
    k_pack<<<(npack + 255) / 256, 256, 0, stream>>>(Whh1, Upk1);

    // 3. layer-0 recurrence -> H0 (S, B, 400)
    k_lstm<<<64, 832, 0, stream>>>(Xg, Upk0, H0);

    // 4. layer-1 input GEMM: Xg = H0 @ Wih1^T + b1   (4096 x 1600, K=400)
    k_gemm_bias<<<gemm_grid, 256, 0, stream>>>(H0, Wih1, b1, Xg,
                                               SEQ * BATCH, NGATE, 2 * HDIM);

    // 5. layer-1 recurrence -> H1
    k_lstm<<<64, 832, 0, stream>>>(Xg, Upk1, H1);

    // 6. output head
    int nout = BATCH * SEQ * 17;
    k_out<<<(nout + 255) / 256, 256, 0, stream>>>(H1, Wo, bo, out);
}